// Round 11
// baseline (100.123 us; speedup 1.0000x reference)
//
#include <hip/hip_runtime.h>
#include <math.h>

constexpr int BATCH = 256;

typedef short short8 __attribute__((ext_vector_type(8)));
typedef float f32x4 __attribute__((ext_vector_type(4)));

// ---------------------------------------------------------------------------
// bf16 helpers (RNE)
// ---------------------------------------------------------------------------
__device__ __forceinline__ unsigned short f2bf(float f) {
    unsigned int u = __float_as_uint(f);
    u += 0x7FFFu + ((u >> 16) & 1u);
    return (unsigned short)(u >> 16);
}
__device__ __forceinline__ float bf2f(unsigned short h) {
    return __uint_as_float(((unsigned int)h) << 16);
}

// ---------------------------------------------------------------------------
// basis_eval: 8 cubic B-spline values + silu. out[0..7]=basis, out[8]=silu.
// (grid rows are identical per problem construction; row ii is used.)
// ---------------------------------------------------------------------------
__device__ __forceinline__ void basis_eval(
    float x, const float* __restrict__ grid, int ii, float out[9])
{
    float g[6];
#pragma unroll
    for (int k = 0; k < 6; ++k) g[k] = grid[(size_t)ii * 6 + k];
    float h = (g[5] - g[0]) * 0.2f;

    float t[12];
    t[0] = g[0] - 3.f * h; t[1] = g[0] - 2.f * h; t[2] = g[0] - h;
#pragma unroll
    for (int k = 0; k < 6; ++k) t[3 + k] = g[k];
    t[9] = g[5] + h; t[10] = g[5] + 2.f * h; t[11] = g[5] + 3.f * h;

    float Bv[11];
#pragma unroll
    for (int j = 0; j < 11; ++j)
        Bv[j] = (x >= t[j] && x < t[j + 1]) ? 1.0f : 0.0f;

#pragma unroll
    for (int d = 1; d <= 3; ++d) {
#pragma unroll
        for (int j = 0; j + d < 11; ++j) {
            float left  = __fdividef(x - t[j],         t[j + d] - t[j]);
            float right = __fdividef(t[j + d + 1] - x, t[j + d + 1] - t[j + 1]);
            Bv[j] = left * Bv[j] + right * Bv[j + 1];
        }
    }

#pragma unroll
    for (int k = 0; k < 8; ++k) out[k] = Bv[k];
    out[8] = __fdividef(x, 1.0f + __expf(-x));
}

// store 12 floats (last 3 zero) as a 24B bf16 record at rec (8B aligned)
__device__ __forceinline__ void store_rec12(unsigned short* rec, const float v[12])
{
    unsigned int u[6];
#pragma unroll
    for (int j = 0; j < 6; ++j)
        u[j] = (unsigned int)f2bf(v[2 * j]) | ((unsigned int)f2bf(v[2 * j + 1]) << 16);
    uint2* p = (uint2*)rec;
    p[0] = make_uint2(u[0], u[1]);
    p[1] = make_uint2(u[2], u[3]);
    p[2] = make_uint2(u[4], u[5]);
}

// load a 24B record -> 9 floats
__device__ __forceinline__ void load_rec12(const unsigned short* rec, float f[9])
{
    const uint2* p = (const uint2*)rec;
    uint2 q0 = p[0], q1 = p[1], q2 = p[2];
    f[0] = bf2f((unsigned short)q0.x); f[1] = bf2f((unsigned short)(q0.x >> 16));
    f[2] = bf2f((unsigned short)q0.y); f[3] = bf2f((unsigned short)(q0.y >> 16));
    f[4] = bf2f((unsigned short)q1.x); f[5] = bf2f((unsigned short)(q1.x >> 16));
    f[6] = bf2f((unsigned short)q1.y); f[7] = bf2f((unsigned short)(q1.y >> 16));
    f[8] = bf2f((unsigned short)q2.x);
}

// ---------------------------------------------------------------------------
// merge: wc9 record s (= o*I+ii): [ssp*coef0..7, sb, 0,0,0] bf16
// ---------------------------------------------------------------------------
__device__ __forceinline__ void merge_body(
    const float* __restrict__ coef, const float* __restrict__ ssp,
    const float* __restrict__ sb, unsigned short* __restrict__ wc9, int s)
{
    float sspv = ssp[s], sbv = sb[s];
    const float4* c = (const float4*)(coef + (size_t)s * 8);
    float4 c0 = c[0], c1 = c[1];
    float v[12] = { sspv * c0.x, sspv * c0.y, sspv * c0.z, sspv * c0.w,
                    sspv * c1.x, sspv * c1.y, sspv * c1.z, sspv * c1.w,
                    sbv, 0.f, 0.f, 0.f };
    store_rec12(wc9 + (size_t)s * 12, v);
}

// ---------------------------------------------------------------------------
// gemm0 fused: D[o][b] = wc9_0[o][:] . bas9_0[b][:]  (K2=3072, full-K chain),
// epilogue: xmid = D + bias0 -> basis_eval -> bas9_1 records (dense writes via
// per-wave LDS 16x17 transpose). 128 blocks (mt in [0,32), nt in [0,4)).
// ---------------------------------------------------------------------------
__device__ __forceinline__ void gemm0_fused(
    const unsigned short* __restrict__ wc9_0, const unsigned short* __restrict__ bas9_0,
    const float* __restrict__ bias0, const float* __restrict__ grid1,
    unsigned short* __restrict__ bas9_1, int bid)
{
    constexpr int K2 = 3072;
    __shared__ float ldsT[4][16 * 17];
    int mt = bid >> 2, nt = bid & 3;
    int t = threadIdx.x, l = t & 63, w = t >> 6;
    int m0 = mt * 16;            // ii (layer-1 input) base
    int n0 = nt * 64 + w * 16;   // b base (per wave)

    const unsigned short* pa = wc9_0  + (size_t)(m0 + (l & 15)) * K2 + ((l >> 4) * 8);
    const unsigned short* pb = bas9_0 + (size_t)(n0 + (l & 15)) * K2 + ((l >> 4) * 8);

    f32x4 acc = {0.f, 0.f, 0.f, 0.f};
#pragma unroll 8
    for (int kk = 0; kk < K2 / 32; ++kk) {
        short8 av = *(const short8*)pa; pa += 32;
        short8 bv = *(const short8*)pb; pb += 32;
        acc = __builtin_amdgcn_mfma_f32_16x16x32_bf16(av, bv, acc, 0, 0, 0);
    }

    float* T = ldsT[w];
#pragma unroll
    for (int r = 0; r < 4; ++r) {
        int ii_loc = (l >> 4) * 4 + r;   // m-local (D row)
        int b_loc  = l & 15;             // n-local (D col)
        T[ii_loc * 17 + b_loc] = acc[r] + bias0[m0 + ii_loc];
    }
    __syncthreads();

    int ii_loc = l & 15;
    int ii = m0 + ii_loc;
#pragma unroll
    for (int j = 0; j < 4; ++j) {
        int b_loc = (l >> 4) * 4 + j;
        float xv = T[ii_loc * 17 + b_loc];
        float out[12];
        basis_eval(xv, grid1, ii, out);
        out[9] = 0.f; out[10] = 0.f; out[11] = 0.f;
        store_rec12(bas9_1 + ((size_t)(n0 + b_loc) * 512 + ii) * 12, out);
    }
}

// ---------------------------------------------------------------------------
// gemm1 fused: D[b][o] = bas9_1[b][:] . wc9_1[o][:]  (K2=6144, full-K chain),
// epilogue: x2[b][o] = D + bias1[o]. 64 blocks (mt in [0,16), nt in [0,4)).
// ---------------------------------------------------------------------------
__device__ __forceinline__ void gemm1_fused(
    const unsigned short* __restrict__ bas9_1, const unsigned short* __restrict__ wc9_1,
    const float* __restrict__ bias1, float* __restrict__ x2, int bid)
{
    constexpr int K2 = 6144;
    int mt = bid >> 2, nt = bid & 3;
    int t = threadIdx.x, l = t & 63, w = t >> 6;
    int m0 = mt * 16;            // b base
    int n0 = nt * 64 + w * 16;   // o base (per wave)

    const unsigned short* pa = bas9_1 + (size_t)(m0 + (l & 15)) * K2 + ((l >> 4) * 8);
    const unsigned short* pb = wc9_1  + (size_t)(n0 + (l & 15)) * K2 + ((l >> 4) * 8);

    f32x4 acc = {0.f, 0.f, 0.f, 0.f};
#pragma unroll 8
    for (int kk = 0; kk < K2 / 32; ++kk) {
        short8 av = *(const short8*)pa; pa += 32;
        short8 bv = *(const short8*)pb; pb += 32;
        acc = __builtin_amdgcn_mfma_f32_16x16x32_bf16(av, bv, acc, 0, 0, 0);
    }

    int o = n0 + (l & 15);
    float bv = bias1[o];
#pragma unroll
    for (int r = 0; r < 4; ++r) {
        int b = m0 + (l >> 4) * 4 + r;
        x2[(size_t)b * 256 + o] = acc[r] + bv;
    }
}

// ---------------------------------------------------------------------------
// stats sweep: thread = ii (ii = isp*256+t), 8 o's in regs, BCH=32 b's/block.
// Reads bf16 records (24B each). spart: [8][3][O*I]
// ---------------------------------------------------------------------------
template <int I, int O>
__device__ __forceinline__ void stats_body(
    const unsigned short* __restrict__ bas9, const unsigned short* __restrict__ wc9,
    float* __restrict__ spart, int og, int ch, int isp)
{
    constexpr int OTB = 8, BCH = 32;
    const size_t OI = (size_t)O * I;
    int ii = isp * 256 + threadIdx.x;

    float wcr[OTB][9];
#pragma unroll
    for (int o = 0; o < OTB; ++o)
        load_rec12(wc9 + ((size_t)(og * OTB + o) * I + ii) * 12, wcr[o]);

    float aab[OTB], asum[OTB], asq[OTB];
#pragma unroll
    for (int o = 0; o < OTB; ++o) { aab[o] = 0.f; asum[o] = 0.f; asq[o] = 0.f; }

    for (int bl = 0; bl < BCH; ++bl) {
        int b = ch * BCH + bl;
        float f[9];
        load_rec12(bas9 + ((size_t)b * I + ii) * 12, f);
#pragma unroll
        for (int o = 0; o < OTB; ++o) {
            float y = wcr[o][8] * f[8];
#pragma unroll
            for (int p = 0; p < 8; ++p) y = fmaf(f[p], wcr[o][p], y);
            aab[o] += fabsf(y);
            asum[o] += y;
            asq[o] = fmaf(y, y, asq[o]);
        }
    }

    size_t cb = (size_t)ch * 3 * OI;
#pragma unroll
    for (int o = 0; o < OTB; ++o) {
        size_t s = (size_t)(og * OTB + o) * I + ii;
        spart[cb + s]          = aab[o];
        spart[cb + OI + s]     = asum[o];
        spart[cb + 2 * OI + s] = asq[o];
    }
}

__device__ __forceinline__ void statsfin_body(
    const float* __restrict__ spart, const float* __restrict__ grid,
    float* __restrict__ sc, float* __restrict__ st, int size, int s)
{
    float ab = 0.f, sm = 0.f, sq = 0.f;
#pragma unroll
    for (int k = 0; k < 8; ++k) {
        size_t base = (size_t)k * 3 * (size_t)size;
        ab += spart[base + s];
        sm += spart[base + (size_t)size + s];
        sq += spart[base + 2 * (size_t)size + s];
    }
    float range = grid[(size_t)s * 6 + 5] - grid[(size_t)s * 6 + 0] + 1e-4f;
    sc[s] = (ab * (1.0f / BATCH)) / range;
    float var = (sq - sm * sm * (1.0f / BATCH)) * (1.0f / (BATCH - 1));
    st[s] = sqrtf(fmaxf(var, 0.0f));
}

// ---------------------------------------------------------------------------
// K1: merge0(512) | merge1(512) | basis0(256, ii-lane-fast)  -> 1280 blocks
// ---------------------------------------------------------------------------
__global__ __launch_bounds__(256) void k1_prep(
    const float* __restrict__ coef0, const float* __restrict__ ssp0,
    const float* __restrict__ sb0, unsigned short* __restrict__ wc9_0,
    const float* __restrict__ coef1, const float* __restrict__ ssp1,
    const float* __restrict__ sb1, unsigned short* __restrict__ wc9_1,
    const float* __restrict__ x, const float* __restrict__ grid0,
    unsigned short* __restrict__ bas9_0)
{
    int bid = blockIdx.x, t = threadIdx.x;
    if (bid < 512)  { merge_body(coef0, ssp0, sb0, wc9_0, bid * 256 + t); return; }
    if (bid < 1024) { merge_body(coef1, ssp1, sb1, wc9_1, (bid - 512) * 256 + t); return; }
    int tile = bid - 1024;                 // 16 bt x 16 it
    int bt = tile >> 4, it = tile & 15;
    int ii = it * 16 + (t & 15), b = bt * 16 + (t >> 4);
    float out[12];
    basis_eval(x[(size_t)b * 256 + ii], grid0, ii, out);
    out[9] = 0.f; out[10] = 0.f; out[11] = 0.f;
    store_rec12(bas9_0 + ((size_t)b * 256 + ii) * 12, out);
}

// ---------------------------------------------------------------------------
// K2: gemm0-fused(128) | stats0(512)                          -> 640 blocks
// ---------------------------------------------------------------------------
__global__ __launch_bounds__(256) void k2_sweep0(
    const unsigned short* __restrict__ wc9_0, const unsigned short* __restrict__ bas9_0,
    const float* __restrict__ bias0, const float* __restrict__ grid1,
    unsigned short* __restrict__ bas9_1, float* __restrict__ spart0)
{
    int bid = blockIdx.x;
    if (bid < 128) {
        gemm0_fused(wc9_0, bas9_0, bias0, grid1, bas9_1, bid);
    } else {
        int r = bid - 128;   // og in [0,64), ch in [0,8)
        stats_body<256, 512>(bas9_0, wc9_0, spart0, r >> 3, r & 7, 0);
    }
}

// ---------------------------------------------------------------------------
// K3: gemm1-fused(64) | stats1(512)                           -> 576 blocks
// ---------------------------------------------------------------------------
__global__ __launch_bounds__(256) void k3_sweep1(
    const unsigned short* __restrict__ bas9_1, const unsigned short* __restrict__ wc9_1,
    const float* __restrict__ bias1, float* __restrict__ x2,
    float* __restrict__ spart1)
{
    int bid = blockIdx.x;
    if (bid < 64) {
        gemm1_fused(bas9_1, wc9_1, bias1, x2, bid);
    } else {
        int r = bid - 64;    // og in [0,32), ch in [0,8), isp in {0,1}
        int og = r >> 4, rem = r & 15;
        stats_body<512, 256>(bas9_1, wc9_1, spart1, og, rem & 7, rem >> 3);
    }
}

// ---------------------------------------------------------------------------
// K4: statsfin0(512) | statsfin1(512)                         -> 1024 blocks
// ---------------------------------------------------------------------------
__global__ __launch_bounds__(256) void k4_fin(
    const float* __restrict__ spart0, const float* __restrict__ grid0,
    float* __restrict__ sc0, float* __restrict__ st0,
    const float* __restrict__ spart1, const float* __restrict__ grid1,
    float* __restrict__ sc1, float* __restrict__ st1)
{
    int bid = blockIdx.x, t = threadIdx.x;
    if (bid < 512) {
        statsfin_body(spart0, grid0, sc0, st0, 131072, bid * 256 + t);
    } else {
        statsfin_body(spart1, grid1, sc1, st1, 131072, (bid - 512) * 256 + t);
    }
}

// ---------------------------------------------------------------------------
extern "C" void kernel_launch(void* const* d_in, const int* in_sizes, int n_in,
                              void* d_out, int out_size, void* d_ws, size_t ws_size,
                              hipStream_t stream)
{
    const float* x     = (const float*)d_in[0];
    const float* grid0 = (const float*)d_in[1];
    const float* coef0 = (const float*)d_in[2];
    const float* sb0   = (const float*)d_in[3];
    const float* ssp0  = (const float*)d_in[4];
    const float* bias0 = (const float*)d_in[5];
    const float* grid1 = (const float*)d_in[6];
    const float* coef1 = (const float*)d_in[7];
    const float* sb1   = (const float*)d_in[8];
    const float* ssp1  = (const float*)d_in[9];
    const float* bias1 = (const float*)d_in[10];

    float* out = (float*)d_out;
    float* x2  = out;                 // (256,256)
    float* sc0 = out + 65536;         // (512,256)
    float* st0 = out + 196608;        // (512,256)
    float* sc1 = out + 327680;        // (256,512)
    float* st1 = out + 458752;        // (256,512)

    // Workspace (~36 MB, all disjoint)
    char* w = (char*)d_ws;
    unsigned short* wc9_0  = (unsigned short*)w; w += (size_t)512 * 3072 * 2;
    unsigned short* wc9_1  = (unsigned short*)w; w += (size_t)256 * 6144 * 2;
    unsigned short* bas9_0 = (unsigned short*)w; w += (size_t)256 * 3072 * 2;
    unsigned short* bas9_1 = (unsigned short*)w; w += (size_t)256 * 6144 * 2;
    float* spart0 = (float*)w; w += (size_t)8 * 3 * 131072 * 4;
    float* spart1 = (float*)w; w += (size_t)8 * 3 * 131072 * 4;

    k1_prep<<<1280, 256, 0, stream>>>(
        coef0, ssp0, sb0, wc9_0, coef1, ssp1, sb1, wc9_1,
        x, grid0, bas9_0);

    k2_sweep0<<<640, 256, 0, stream>>>(
        wc9_0, bas9_0, bias0, grid1, bas9_1, spart0);

    k3_sweep1<<<576, 256, 0, stream>>>(
        bas9_1, wc9_1, bias1, x2, spart1);

    k4_fin<<<1024, 256, 0, stream>>>(
        spart0, grid0, sc0, st0, spart1, grid1, sc1, st1);
}

// Round 12
// 70.963 us; speedup vs baseline: 1.4109x; 1.4109x over previous
//
#include <hip/hip_runtime.h>
#include <math.h>

constexpr int BATCH = 256;

typedef short short8 __attribute__((ext_vector_type(8)));
typedef float f32x4 __attribute__((ext_vector_type(4)));

// ---------------------------------------------------------------------------
// bf16 helpers (RNE)
// ---------------------------------------------------------------------------
__device__ __forceinline__ unsigned short f2bf(float f) {
    unsigned int u = __float_as_uint(f);
    u += 0x7FFFu + ((u >> 16) & 1u);
    return (unsigned short)(u >> 16);
}
__device__ __forceinline__ float bf2f(unsigned short h) {
    return __uint_as_float(((unsigned int)h) << 16);
}

// ---------------------------------------------------------------------------
// basis_eval: 8 cubic B-spline values + silu. out[0..7]=basis, out[8]=silu.
// ---------------------------------------------------------------------------
__device__ __forceinline__ void basis_eval(
    float x, const float* __restrict__ grid, int ii, float out[9])
{
    float g[6];
#pragma unroll
    for (int k = 0; k < 6; ++k) g[k] = grid[(size_t)ii * 6 + k];
    float h = (g[5] - g[0]) * 0.2f;

    float t[12];
    t[0] = g[0] - 3.f * h; t[1] = g[0] - 2.f * h; t[2] = g[0] - h;
#pragma unroll
    for (int k = 0; k < 6; ++k) t[3 + k] = g[k];
    t[9] = g[5] + h; t[10] = g[5] + 2.f * h; t[11] = g[5] + 3.f * h;

    float Bv[11];
#pragma unroll
    for (int j = 0; j < 11; ++j)
        Bv[j] = (x >= t[j] && x < t[j + 1]) ? 1.0f : 0.0f;

#pragma unroll
    for (int d = 1; d <= 3; ++d) {
#pragma unroll
        for (int j = 0; j + d < 11; ++j) {
            float left  = __fdividef(x - t[j],         t[j + d] - t[j]);
            float right = __fdividef(t[j + d + 1] - x, t[j + d + 1] - t[j + 1]);
            Bv[j] = left * Bv[j] + right * Bv[j + 1];
        }
    }

#pragma unroll
    for (int k = 0; k < 8; ++k) out[k] = Bv[k];
    out[8] = __fdividef(x, 1.0f + __expf(-x));
}

// store 12 floats (last 3 zero) as a 24B bf16 record at rec (8B aligned)
__device__ __forceinline__ void store_rec12(unsigned short* rec, const float v[12])
{
    unsigned int u[6];
#pragma unroll
    for (int j = 0; j < 6; ++j)
        u[j] = (unsigned int)f2bf(v[2 * j]) | ((unsigned int)f2bf(v[2 * j + 1]) << 16);
    uint2* p = (uint2*)rec;
    p[0] = make_uint2(u[0], u[1]);
    p[1] = make_uint2(u[2], u[3]);
    p[2] = make_uint2(u[4], u[5]);
}

// load a 24B record -> 9 floats
__device__ __forceinline__ void load_rec12(const unsigned short* rec, float f[9])
{
    const uint2* p = (const uint2*)rec;
    uint2 q0 = p[0], q1 = p[1], q2 = p[2];
    f[0] = bf2f((unsigned short)q0.x); f[1] = bf2f((unsigned short)(q0.x >> 16));
    f[2] = bf2f((unsigned short)q0.y); f[3] = bf2f((unsigned short)(q0.y >> 16));
    f[4] = bf2f((unsigned short)q1.x); f[5] = bf2f((unsigned short)(q1.x >> 16));
    f[6] = bf2f((unsigned short)q1.y); f[7] = bf2f((unsigned short)(q1.y >> 16));
    f[8] = bf2f((unsigned short)q2.x);
}

// ---------------------------------------------------------------------------
// merge: wc9 record s (= o*I+ii): [ssp*coef0..7, sb, 0,0,0] bf16
// ---------------------------------------------------------------------------
__device__ __forceinline__ void merge_body(
    const float* __restrict__ coef, const float* __restrict__ ssp,
    const float* __restrict__ sb, unsigned short* __restrict__ wc9, int s)
{
    float sspv = ssp[s], sbv = sb[s];
    const float4* c = (const float4*)(coef + (size_t)s * 8);
    float4 c0 = c[0], c1 = c[1];
    float v[12] = { sspv * c0.x, sspv * c0.y, sspv * c0.z, sspv * c0.w,
                    sspv * c1.x, sspv * c1.y, sspv * c1.z, sspv * c1.w,
                    sbv, 0.f, 0.f, 0.f };
    store_rec12(wc9 + (size_t)s * 12, v);
}

// ---------------------------------------------------------------------------
// gemm0 fused (512 blocks = 32 mt x 16 nt): one 16x16 tile (m=ii, n=b),
// 4 waves split K (K2=3072 -> 24-MFMA chain each), LDS 16x17 reduce.
// Epilogue: xmid = D + bias0 -> basis_eval -> bas9_1 records (dense writes).
// ---------------------------------------------------------------------------
__device__ __forceinline__ void gemm0_fused(
    const unsigned short* __restrict__ wc9_0, const unsigned short* __restrict__ bas9_0,
    const float* __restrict__ bias0, const float* __restrict__ grid1,
    unsigned short* __restrict__ bas9_1, int bid)
{
    constexpr int K2 = 3072, KW = K2 / 4;
    __shared__ float T[4][16][17];
    int mt = bid >> 4, nt = bid & 15;
    int t = threadIdx.x, l = t & 63, w = t >> 6;
    int m0 = mt * 16;            // ii base (layer-1 input)
    int n0 = nt * 16;            // b base

    const unsigned short* pa = wc9_0  + (size_t)(m0 + (l & 15)) * K2 + w * KW + ((l >> 4) * 8);
    const unsigned short* pb = bas9_0 + (size_t)(n0 + (l & 15)) * K2 + w * KW + ((l >> 4) * 8);

    f32x4 acc = {0.f, 0.f, 0.f, 0.f};
#pragma unroll 8
    for (int kk = 0; kk < KW / 32; ++kk) {   // 24 steps
        short8 av = *(const short8*)pa; pa += 32;
        short8 bv = *(const short8*)pb; pb += 32;
        acc = __builtin_amdgcn_mfma_f32_16x16x32_bf16(av, bv, acc, 0, 0, 0);
    }

#pragma unroll
    for (int r = 0; r < 4; ++r)
        T[w][(l >> 4) * 4 + r][l & 15] = acc[r];   // [m_loc][n_loc]
    __syncthreads();

    int ii_loc = t & 15, b_loc = t >> 4;     // thread owns one element
    float d = T[0][ii_loc][b_loc] + T[1][ii_loc][b_loc]
            + T[2][ii_loc][b_loc] + T[3][ii_loc][b_loc];
    int ii = m0 + ii_loc;
    float xv = d + bias0[ii];
    float out[12];
    basis_eval(xv, grid1, ii, out);
    out[9] = 0.f; out[10] = 0.f; out[11] = 0.f;
    store_rec12(bas9_1 + ((size_t)(n0 + b_loc) * 512 + ii) * 12, out);
}

// ---------------------------------------------------------------------------
// gemm1 fused (256 blocks = 16 mt x 16 nt): one 16x16 tile (m=b, n=o),
// 4 waves split K (K2=6144 -> 48-MFMA chain each), LDS reduce.
// Epilogue: x2[b][o] = D + bias1[o].
// ---------------------------------------------------------------------------
__device__ __forceinline__ void gemm1_fused(
    const unsigned short* __restrict__ bas9_1, const unsigned short* __restrict__ wc9_1,
    const float* __restrict__ bias1, float* __restrict__ x2, int bid)
{
    constexpr int K2 = 6144, KW = K2 / 4;
    __shared__ float T[4][16][17];
    int mt = bid >> 4, nt = bid & 15;
    int t = threadIdx.x, l = t & 63, w = t >> 6;
    int m0 = mt * 16;            // b base
    int n0 = nt * 16;            // o base

    const unsigned short* pa = bas9_1 + (size_t)(m0 + (l & 15)) * K2 + w * KW + ((l >> 4) * 8);
    const unsigned short* pb = wc9_1  + (size_t)(n0 + (l & 15)) * K2 + w * KW + ((l >> 4) * 8);

    f32x4 acc = {0.f, 0.f, 0.f, 0.f};
#pragma unroll 8
    for (int kk = 0; kk < KW / 32; ++kk) {   // 48 steps
        short8 av = *(const short8*)pa; pa += 32;
        short8 bv = *(const short8*)pb; pb += 32;
        acc = __builtin_amdgcn_mfma_f32_16x16x32_bf16(av, bv, acc, 0, 0, 0);
    }

#pragma unroll
    for (int r = 0; r < 4; ++r)
        T[w][(l >> 4) * 4 + r][l & 15] = acc[r];   // [b_loc][o_loc]
    __syncthreads();

    int o_loc = t & 15, b_loc = t >> 4;
    float d = T[0][b_loc][o_loc] + T[1][b_loc][o_loc]
            + T[2][b_loc][o_loc] + T[3][b_loc][o_loc];
    int o = n0 + o_loc;
    x2[(size_t)(m0 + b_loc) * 256 + o] = d + bias1[o];
}

// ---------------------------------------------------------------------------
// stats sweep: thread = ii (ii = isp*256+t), 8 o's in regs, BCH=32 b's/block.
// Reads bf16 records (24B each). spart: [8][3][O*I]
// ---------------------------------------------------------------------------
template <int I, int O>
__device__ __forceinline__ void stats_body(
    const unsigned short* __restrict__ bas9, const unsigned short* __restrict__ wc9,
    float* __restrict__ spart, int og, int ch, int isp)
{
    constexpr int OTB = 8, BCH = 32;
    const size_t OI = (size_t)O * I;
    int ii = isp * 256 + threadIdx.x;

    float wcr[OTB][9];
#pragma unroll
    for (int o = 0; o < OTB; ++o)
        load_rec12(wc9 + ((size_t)(og * OTB + o) * I + ii) * 12, wcr[o]);

    float aab[OTB], asum[OTB], asq[OTB];
#pragma unroll
    for (int o = 0; o < OTB; ++o) { aab[o] = 0.f; asum[o] = 0.f; asq[o] = 0.f; }

    for (int bl = 0; bl < BCH; ++bl) {
        int b = ch * BCH + bl;
        float f[9];
        load_rec12(bas9 + ((size_t)b * I + ii) * 12, f);
#pragma unroll
        for (int o = 0; o < OTB; ++o) {
            float y = wcr[o][8] * f[8];
#pragma unroll
            for (int p = 0; p < 8; ++p) y = fmaf(f[p], wcr[o][p], y);
            aab[o] += fabsf(y);
            asum[o] += y;
            asq[o] = fmaf(y, y, asq[o]);
        }
    }

    size_t cb = (size_t)ch * 3 * OI;
#pragma unroll
    for (int o = 0; o < OTB; ++o) {
        size_t s = (size_t)(og * OTB + o) * I + ii;
        spart[cb + s]          = aab[o];
        spart[cb + OI + s]     = asum[o];
        spart[cb + 2 * OI + s] = asq[o];
    }
}

__device__ __forceinline__ void statsfin_body(
    const float* __restrict__ spart, const float* __restrict__ grid,
    float* __restrict__ sc, float* __restrict__ st, int size, int s)
{
    float ab = 0.f, sm = 0.f, sq = 0.f;
#pragma unroll
    for (int k = 0; k < 8; ++k) {
        size_t base = (size_t)k * 3 * (size_t)size;
        ab += spart[base + s];
        sm += spart[base + (size_t)size + s];
        sq += spart[base + 2 * (size_t)size + s];
    }
    float range = grid[(size_t)s * 6 + 5] - grid[(size_t)s * 6 + 0] + 1e-4f;
    sc[s] = (ab * (1.0f / BATCH)) / range;
    float var = (sq - sm * sm * (1.0f / BATCH)) * (1.0f / (BATCH - 1));
    st[s] = sqrtf(fmaxf(var, 0.0f));
}

// ---------------------------------------------------------------------------
// K1: merge0(512) | merge1(512) | basis0(256, ii-lane-fast)  -> 1280 blocks
// ---------------------------------------------------------------------------
__global__ __launch_bounds__(256) void k1_prep(
    const float* __restrict__ coef0, const float* __restrict__ ssp0,
    const float* __restrict__ sb0, unsigned short* __restrict__ wc9_0,
    const float* __restrict__ coef1, const float* __restrict__ ssp1,
    const float* __restrict__ sb1, unsigned short* __restrict__ wc9_1,
    const float* __restrict__ x, const float* __restrict__ grid0,
    unsigned short* __restrict__ bas9_0)
{
    int bid = blockIdx.x, t = threadIdx.x;
    if (bid < 512)  { merge_body(coef0, ssp0, sb0, wc9_0, bid * 256 + t); return; }
    if (bid < 1024) { merge_body(coef1, ssp1, sb1, wc9_1, (bid - 512) * 256 + t); return; }
    int tile = bid - 1024;                 // 16 bt x 16 it
    int bt = tile >> 4, it = tile & 15;
    int ii = it * 16 + (t & 15), b = bt * 16 + (t >> 4);
    float out[12];
    basis_eval(x[(size_t)b * 256 + ii], grid0, ii, out);
    out[9] = 0.f; out[10] = 0.f; out[11] = 0.f;
    store_rec12(bas9_0 + ((size_t)b * 256 + ii) * 12, out);
}

// ---------------------------------------------------------------------------
// K2: gemm0-fused(512) | stats0(512)                         -> 1024 blocks
// ---------------------------------------------------------------------------
__global__ __launch_bounds__(256) void k2_sweep0(
    const unsigned short* __restrict__ wc9_0, const unsigned short* __restrict__ bas9_0,
    const float* __restrict__ bias0, const float* __restrict__ grid1,
    unsigned short* __restrict__ bas9_1, float* __restrict__ spart0)
{
    int bid = blockIdx.x;
    if (bid < 512) {
        gemm0_fused(wc9_0, bas9_0, bias0, grid1, bas9_1, bid);
    } else {
        int r = bid - 512;   // og in [0,64), ch in [0,8)
        stats_body<256, 512>(bas9_0, wc9_0, spart0, r >> 3, r & 7, 0);
    }
}

// ---------------------------------------------------------------------------
// K3: gemm1-fused(256) | stats1(512)                         -> 768 blocks
// ---------------------------------------------------------------------------
__global__ __launch_bounds__(256) void k3_sweep1(
    const unsigned short* __restrict__ bas9_1, const unsigned short* __restrict__ wc9_1,
    const float* __restrict__ bias1, float* __restrict__ x2,
    float* __restrict__ spart1)
{
    int bid = blockIdx.x;
    if (bid < 256) {
        gemm1_fused(bas9_1, wc9_1, bias1, x2, bid);
    } else {
        int r = bid - 256;   // og in [0,32), ch in [0,8), isp in {0,1}
        int og = r >> 4, rem = r & 15;
        stats_body<512, 256>(bas9_1, wc9_1, spart1, og, rem & 7, rem >> 3);
    }
}

// ---------------------------------------------------------------------------
// K4: statsfin0(512) | statsfin1(512)                        -> 1024 blocks
// ---------------------------------------------------------------------------
__global__ __launch_bounds__(256) void k4_fin(
    const float* __restrict__ spart0, const float* __restrict__ grid0,
    float* __restrict__ sc0, float* __restrict__ st0,
    const float* __restrict__ spart1, const float* __restrict__ grid1,
    float* __restrict__ sc1, float* __restrict__ st1)
{
    int bid = blockIdx.x, t = threadIdx.x;
    if (bid < 512) {
        statsfin_body(spart0, grid0, sc0, st0, 131072, bid * 256 + t);
    } else {
        statsfin_body(spart1, grid1, sc1, st1, 131072, (bid - 512) * 256 + t);
    }
}

// ---------------------------------------------------------------------------
extern "C" void kernel_launch(void* const* d_in, const int* in_sizes, int n_in,
                              void* d_out, int out_size, void* d_ws, size_t ws_size,
                              hipStream_t stream)
{
    const float* x     = (const float*)d_in[0];
    const float* grid0 = (const float*)d_in[1];
    const float* coef0 = (const float*)d_in[2];
    const float* sb0   = (const float*)d_in[3];
    const float* ssp0  = (const float*)d_in[4];
    const float* bias0 = (const float*)d_in[5];
    const float* grid1 = (const float*)d_in[6];
    const float* coef1 = (const float*)d_in[7];
    const float* sb1   = (const float*)d_in[8];
    const float* ssp1  = (const float*)d_in[9];
    const float* bias1 = (const float*)d_in[10];

    float* out = (float*)d_out;
    float* x2  = out;                 // (256,256)
    float* sc0 = out + 65536;         // (512,256)
    float* st0 = out + 196608;        // (512,256)
    float* sc1 = out + 327680;        // (256,512)
    float* st1 = out + 458752;        // (256,512)

    // Workspace (~36 MB, all disjoint)
    char* w = (char*)d_ws;
    unsigned short* wc9_0  = (unsigned short*)w; w += (size_t)512 * 3072 * 2;
    unsigned short* wc9_1  = (unsigned short*)w; w += (size_t)256 * 6144 * 2;
    unsigned short* bas9_0 = (unsigned short*)w; w += (size_t)256 * 3072 * 2;
    unsigned short* bas9_1 = (unsigned short*)w; w += (size_t)256 * 6144 * 2;
    float* spart0 = (float*)w; w += (size_t)8 * 3 * 131072 * 4;
    float* spart1 = (float*)w; w += (size_t)8 * 3 * 131072 * 4;

    k1_prep<<<1280, 256, 0, stream>>>(
        coef0, ssp0, sb0, wc9_0, coef1, ssp1, sb1, wc9_1,
        x, grid0, bas9_0);

    k2_sweep0<<<1024, 256, 0, stream>>>(
        wc9_0, bas9_0, bias0, grid1, bas9_1, spart0);

    k3_sweep1<<<768, 256, 0, stream>>>(
        bas9_1, wc9_1, bias1, x2, spart1);

    k4_fin<<<1024, 256, 0, stream>>>(
        spart0, grid0, sc0, st0, spart1, grid1, sc1, st1);
}